// Round 1
// baseline (4268.303 us; speedup 1.0000x reference)
//
#include <hip/hip_runtime.h>

// Problem constants (fixed-shape problem)
constexpr int N_    = 8;
constexpr int M_    = 50000;
constexpr int FIN_  = 16;
constexpr int FOUT_ = 32;
constexpr int KCH_  = 4;
constexpr int NNZ_  = 800000;
constexpr int ROW_  = FIN_ * N_;   // 128 floats per term row

// ---------------------------------------------------------------------------
// X0[m, f*8+n] = x[n, m, f]
__global__ void k_build_x0(const float* __restrict__ x, float* __restrict__ t0) {
    int t = blockIdx.x * blockDim.x + threadIdx.x;
    if (t >= M_ * ROW_) return;
    int m = t >> 7;            // / 128
    int c = t & 127;
    int f = c >> 3;            // / 8
    int n = c & 7;
    t0[t] = x[((size_t)n * M_ + m) * FIN_ + f];
}

// buf = -buf  (prep for T_k = 2*spmm(T_{k-1}) - T_{k-2}, accumulated in place)
__global__ void k_negate(float* __restrict__ buf) {
    int t = blockIdx.x * blockDim.x + threadIdx.x;
    if (t >= M_ * ROW_) return;
    buf[t] = -buf[t];
}

// Y[row[i], :] += scale * vals[i] * X[col[i], :]
// 32 threads per nnz, 4 columns each (float4 gather + 4 atomics)
__global__ void k_spmm_atomic(const float* __restrict__ X, float* __restrict__ Y,
                              const float* __restrict__ vals,
                              const int* __restrict__ row,
                              const int* __restrict__ col,
                              float scale) {
    int t = blockIdx.x * blockDim.x + threadIdx.x;
    if (t >= NNZ_ * (ROW_ / 4)) return;
    int i  = t >> 5;           // nnz index
    int c4 = (t & 31) * 4;     // column base
    float v = vals[i] * scale;
    int r = row[i];
    int c = col[i];
    const float4 xv = *reinterpret_cast<const float4*>(X + (size_t)c * ROW_ + c4);
    float* y = Y + (size_t)r * ROW_ + c4;
    atomicAdd(y + 0, v * xv.x);
    atomicAdd(y + 1, v * xv.y);
    atomicAdd(y + 2, v * xv.z);
    atomicAdd(y + 3, v * xv.w);
}

// out[n,m,o] (+)= sum_f T[m, f*8+n] * w[f,k,o]   (+ b[o] on init pass)
__global__ void k_accum(const float* __restrict__ T, const float* __restrict__ w,
                        const float* __restrict__ b, float* __restrict__ out,
                        int k, int init) {
    int t = blockIdx.x * blockDim.x + threadIdx.x;
    if (t >= N_ * M_ * FOUT_) return;
    int o  = t & 31;
    int nm = t >> 5;
    int m  = nm % M_;
    int n  = nm / M_;
    const float* tr = T + (size_t)m * ROW_ + n;
    float acc = init ? b[o] : out[t];
#pragma unroll
    for (int f = 0; f < FIN_; ++f)
        acc += tr[f * 8] * w[(f * KCH_ + k) * FOUT_ + o];
    out[t] = acc;
}

// ---------------------------------------------------------------------------
extern "C" void kernel_launch(void* const* d_in, const int* in_sizes, int n_in,
                              void* d_out, int out_size, void* d_ws, size_t ws_size,
                              hipStream_t stream) {
    const float* x    = (const float*)d_in[0];
    const float* vals = (const float*)d_in[1];
    const float* w    = (const float*)d_in[2];
    const float* b    = (const float*)d_in[3];
    const int*   row  = (const int*)d_in[4];
    const int*   col  = (const int*)d_in[5];
    float* out = (float*)d_out;

    float* A = (float*)d_ws;                       // term buffer (25.6 MB)
    float* B = A + (size_t)M_ * ROW_;              // term buffer (25.6 MB)

    const int TB = 256;
    const int nT    = M_ * ROW_;                   // 6.4M elems per term buffer
    const int nO    = N_ * M_ * FOUT_;             // 12.8M output elems
    const int nSp   = NNZ_ * (ROW_ / 4);           // 25.6M spmm threads
    dim3 gT((nT + TB - 1) / TB), gO((nO + TB - 1) / TB), gS((nSp + TB - 1) / TB), blk(TB);

    // T0 = X0
    hipLaunchKernelGGL(k_build_x0, gT, blk, 0, stream, x, A);
    hipLaunchKernelGGL(k_accum,    gO, blk, 0, stream, A, w, b, out, 0, 1);

    // T1 = spmm(T0)
    hipMemsetAsync(B, 0, (size_t)nT * sizeof(float), stream);
    hipLaunchKernelGGL(k_spmm_atomic, gS, blk, 0, stream, A, B, vals, row, col, 1.0f);
    hipLaunchKernelGGL(k_accum,       gO, blk, 0, stream, B, w, b, out, 1, 0);

    // T2 = 2*spmm(T1) - T0   (A := -A, then accumulate)
    hipLaunchKernelGGL(k_negate,      gT, blk, 0, stream, A);
    hipLaunchKernelGGL(k_spmm_atomic, gS, blk, 0, stream, B, A, vals, row, col, 2.0f);
    hipLaunchKernelGGL(k_accum,       gO, blk, 0, stream, A, w, b, out, 2, 0);

    // T3 = 2*spmm(T2) - T1   (B := -B, then accumulate)
    hipLaunchKernelGGL(k_negate,      gT, blk, 0, stream, B);
    hipLaunchKernelGGL(k_spmm_atomic, gS, blk, 0, stream, A, B, vals, row, col, 2.0f);
    hipLaunchKernelGGL(k_accum,       gO, blk, 0, stream, B, w, b, out, 3, 0);
}

// Round 2
// 548.608 us; speedup vs baseline: 7.7802x; 7.7802x over previous
//
#include <hip/hip_runtime.h>

// Problem constants (fixed-shape problem)
constexpr int N_    = 8;
constexpr int M_    = 50000;
constexpr int FIN_  = 16;
constexpr int FOUT_ = 32;
constexpr int KCH_  = 4;
constexpr int NNZ_  = 800000;
constexpr int ROW_  = FIN_ * N_;   // 128 floats per term row

// ---------------------------------------------------------------------------
// X0[m, f*8+n] = x[n, m, f]
__global__ void k_build_x0(const float* __restrict__ x, float* __restrict__ t0) {
    int t = blockIdx.x * blockDim.x + threadIdx.x;
    if (t >= M_ * ROW_) return;
    int m = t >> 7;            // / 128
    int c = t & 127;
    int f = c >> 3;            // / 8
    int n = c & 7;
    t0[t] = x[((size_t)n * M_ + m) * FIN_ + f];
}

// row histogram
__global__ void k_hist(const int* __restrict__ row, int* __restrict__ cnt) {
    int i = blockIdx.x * blockDim.x + threadIdx.x;
    if (i < NNZ_) atomicAdd(&cnt[row[i]], 1);
}

// single-block exclusive scan of cnt[M] -> row_ptr[M+1] and row_tmp[M].
// cnt MAY ALIAS row_tmp: each element is read before it is overwritten
// (same thread, read-then-write order below).
__global__ void k_scan(const int* __restrict__ cnt, int* __restrict__ row_ptr,
                       int* __restrict__ row_tmp) {
    __shared__ int part[256];
    const int t  = threadIdx.x;
    const int CH = (M_ + 255) / 256;
    const int base = t * CH;
    int s = 0;
    for (int i = 0; i < CH; ++i) {
        int idx = base + i;
        if (idx < M_) s += cnt[idx];
    }
    part[t] = s;
    __syncthreads();
    if (t == 0) {
        int run = 0;
        for (int i = 0; i < 256; ++i) { int v = part[i]; part[i] = run; run += v; }
    }
    __syncthreads();
    int run = part[t];
    for (int i = 0; i < CH; ++i) {
        int idx = base + i;
        if (idx < M_) {
            int c = cnt[idx];          // read BEFORE aliased write
            row_ptr[idx] = run;
            row_tmp[idx] = run;
            run += c;
        }
    }
    if (t == 0) row_ptr[M_] = NNZ_;
}

// scatter nnz into CSR order
__global__ void k_scatter(const float* __restrict__ vals, const int* __restrict__ row,
                          const int* __restrict__ col, int* __restrict__ row_tmp,
                          float* __restrict__ cval, int* __restrict__ ccol) {
    int i = blockIdx.x * blockDim.x + threadIdx.x;
    if (i >= NNZ_) return;
    int p = atomicAdd(&row_tmp[row[i]], 1);
    cval[p] = vals[i];
    ccol[p] = col[i];
}

// Y[r,:] = scale * sum_j cval[j]*X[ccol[j],:]  (- prev[r,:] if prev != null)
// one 32-lane group per row, float4 per lane
__global__ void k_spmm_csr(const float* __restrict__ X, const float* __restrict__ prev,
                           float* __restrict__ Y, const int* __restrict__ rp,
                           const float* __restrict__ cval, const int* __restrict__ ccol,
                           float scale) {
    int r = blockIdx.x * (blockDim.x >> 5) + (threadIdx.x >> 5);
    if (r >= M_) return;
    int c4 = (threadIdx.x & 31) * 4;
    float4 acc;
    if (prev) {
        float4 p = *reinterpret_cast<const float4*>(prev + (size_t)r * ROW_ + c4);
        acc = make_float4(-p.x, -p.y, -p.z, -p.w);
    } else {
        acc = make_float4(0.f, 0.f, 0.f, 0.f);
    }
    int e = rp[r + 1];
    for (int j = rp[r]; j < e; ++j) {
        float v = scale * cval[j];
        int   c = ccol[j];
        float4 xv = *reinterpret_cast<const float4*>(X + (size_t)c * ROW_ + c4);
        acc.x += v * xv.x;
        acc.y += v * xv.y;
        acc.z += v * xv.z;
        acc.w += v * xv.w;
    }
    *reinterpret_cast<float4*>(Y + (size_t)r * ROW_ + c4) = acc;
}

// fused final einsum over all 4 terms: thread = (m, o), computes 8 n-outputs
__global__ void k_final(const float* __restrict__ T0, const float* __restrict__ T1,
                        const float* __restrict__ T2, const float* __restrict__ T3,
                        const float* __restrict__ w, const float* __restrict__ b,
                        float* __restrict__ out) {
    int t = blockIdx.x * blockDim.x + threadIdx.x;
    if (t >= M_ * FOUT_) return;
    int o = t & 31;
    int m = t >> 5;
    float acc[8];
    float bias = b[o];
#pragma unroll
    for (int n = 0; n < 8; ++n) acc[n] = bias;
    const float* Ts[4] = {T0, T1, T2, T3};
#pragma unroll
    for (int k = 0; k < 4; ++k) {
        const float* tr = Ts[k] + (size_t)m * ROW_;
#pragma unroll
        for (int f = 0; f < FIN_; ++f) {
            float wk = w[(f * KCH_ + k) * FOUT_ + o];
            float4 a0 = *reinterpret_cast<const float4*>(tr + f * 8);
            float4 a1 = *reinterpret_cast<const float4*>(tr + f * 8 + 4);
            acc[0] += a0.x * wk; acc[1] += a0.y * wk;
            acc[2] += a0.z * wk; acc[3] += a0.w * wk;
            acc[4] += a1.x * wk; acc[5] += a1.y * wk;
            acc[6] += a1.z * wk; acc[7] += a1.w * wk;
        }
    }
#pragma unroll
    for (int n = 0; n < 8; ++n)
        out[((size_t)n * M_ + m) * FOUT_ + o] = acc[n];
}

// per-term accumulation (fallback path, small ws): thread = (m, o), 8 n-outputs
__global__ void k_accum(const float* __restrict__ T, const float* __restrict__ w,
                        const float* __restrict__ b, float* __restrict__ out,
                        int k, int init) {
    int t = blockIdx.x * blockDim.x + threadIdx.x;
    if (t >= M_ * FOUT_) return;
    int o = t & 31;
    int m = t >> 5;
    float acc[8];
    if (init) {
        float bias = b[o];
#pragma unroll
        for (int n = 0; n < 8; ++n) acc[n] = bias;
    } else {
#pragma unroll
        for (int n = 0; n < 8; ++n) acc[n] = out[((size_t)n * M_ + m) * FOUT_ + o];
    }
    const float* tr = T + (size_t)m * ROW_;
#pragma unroll
    for (int f = 0; f < FIN_; ++f) {
        float wk = w[(f * KCH_ + k) * FOUT_ + o];
        float4 a0 = *reinterpret_cast<const float4*>(tr + f * 8);
        float4 a1 = *reinterpret_cast<const float4*>(tr + f * 8 + 4);
        acc[0] += a0.x * wk; acc[1] += a0.y * wk;
        acc[2] += a0.z * wk; acc[3] += a0.w * wk;
        acc[4] += a1.x * wk; acc[5] += a1.y * wk;
        acc[6] += a1.z * wk; acc[7] += a1.w * wk;
    }
#pragma unroll
    for (int n = 0; n < 8; ++n)
        out[((size_t)n * M_ + m) * FOUT_ + o] = acc[n];
}

// ---------------------------------------------------------------------------
extern "C" void kernel_launch(void* const* d_in, const int* in_sizes, int n_in,
                              void* d_out, int out_size, void* d_ws, size_t ws_size,
                              hipStream_t stream) {
    const float* x    = (const float*)d_in[0];
    const float* vals = (const float*)d_in[1];
    const float* w    = (const float*)d_in[2];
    const float* b    = (const float*)d_in[3];
    const int*   row  = (const int*)d_in[4];
    const int*   col  = (const int*)d_in[5];
    float* out = (float*)d_out;

    const size_t tElems = (size_t)M_ * ROW_;             // 6.4M floats per term
    const size_t csrBytes = (size_t)(M_ + 1) * 4 + (size_t)M_ * 4
                          + (size_t)NNZ_ * 4 + (size_t)NNZ_ * 4;
    const size_t fusedBytes = 4 * tElems * 4 + csrBytes; // ~109 MB
    const bool fused = ws_size >= fusedBytes;

    float* T0 = (float*)d_ws;
    float* T1 = T0 + tElems;
    float* T2 = fused ? (T1 + tElems) : nullptr;
    float* T3 = fused ? (T2 + tElems) : nullptr;
    char*  p  = (char*)(fused ? (T3 + tElems) : (T1 + tElems));
    int*   row_ptr = (int*)p;              p += (size_t)(M_ + 1) * 4;
    int*   row_tmp = (int*)p;              p += (size_t)M_ * 4;
    float* cval    = (float*)p;            p += (size_t)NNZ_ * 4;
    int*   ccol    = (int*)p;

    const int TB = 256;
    dim3 blk(TB);
    dim3 gT(((int)tElems + TB - 1) / TB);          // term-sized elementwise
    dim3 gN((NNZ_ + TB - 1) / TB);                 // per-nnz
    dim3 gR((M_ * 32 + TB - 1) / TB);              // 32 lanes per row
    dim3 gF((M_ * FOUT_ + TB - 1) / TB);           // (m,o) threads

    // ---- build CSR (per call) ----
    hipMemsetAsync(row_tmp, 0, (size_t)M_ * 4, stream);     // row_tmp doubles as cnt
    hipLaunchKernelGGL(k_hist,    gN, blk, 0, stream, row, row_tmp);
    hipLaunchKernelGGL(k_scan,    dim3(1), blk, 0, stream, row_tmp, row_ptr, row_tmp);
    hipLaunchKernelGGL(k_scatter, gN, blk, 0, stream, vals, row, col, row_tmp, cval, ccol);

    // ---- Chebyshev terms ----
    hipLaunchKernelGGL(k_build_x0, gT, blk, 0, stream, x, T0);
    hipLaunchKernelGGL(k_spmm_csr, gR, blk, 0, stream, T0, (const float*)nullptr, T1,
                       row_ptr, cval, ccol, 1.0f);

    if (fused) {
        hipLaunchKernelGGL(k_spmm_csr, gR, blk, 0, stream, T1, T0, T2,
                           row_ptr, cval, ccol, 2.0f);
        hipLaunchKernelGGL(k_spmm_csr, gR, blk, 0, stream, T2, T1, T3,
                           row_ptr, cval, ccol, 2.0f);
        hipLaunchKernelGGL(k_final, gF, blk, 0, stream, T0, T1, T2, T3, w, b, out);
    } else {
        hipLaunchKernelGGL(k_accum, gF, blk, 0, stream, T0, w, b, out, 0, 1);
        hipLaunchKernelGGL(k_accum, gF, blk, 0, stream, T1, w, b, out, 1, 0);
        hipLaunchKernelGGL(k_spmm_csr, gR, blk, 0, stream, T1, T0, T0,
                           row_ptr, cval, ccol, 2.0f);   // T2 overwrites T0
        hipLaunchKernelGGL(k_accum, gF, blk, 0, stream, T0, w, b, out, 2, 0);
        hipLaunchKernelGGL(k_spmm_csr, gR, blk, 0, stream, T0, T1, T1,
                           row_ptr, cval, ccol, 2.0f);   // T3 overwrites T1
        hipLaunchKernelGGL(k_accum, gF, blk, 0, stream, T1, w, b, out, 3, 0);
    }
}

// Round 3
// 417.024 us; speedup vs baseline: 10.2351x; 1.3155x over previous
//
#include <hip/hip_runtime.h>

// Problem constants (fixed-shape problem)
constexpr int N_    = 8;
constexpr int M_    = 50000;
constexpr int FIN_  = 16;
constexpr int FOUT_ = 32;
constexpr int KCH_  = 4;
constexpr int NNZ_  = 800000;
constexpr int ROW_  = FIN_ * N_;   // 128 floats per term row
constexpr int SCAN_NB = (M_ + 255) / 256;   // 196 scan blocks

// ---------------------------------------------------------------------------
// X0[m, f*8+n] = x[n, m, f]
__global__ void k_build_x0(const float* __restrict__ x, float* __restrict__ t0) {
    int t = blockIdx.x * blockDim.x + threadIdx.x;
    if (t >= M_ * ROW_) return;
    int m = t >> 7;            // / 128
    int c = t & 127;
    int f = c >> 3;            // / 8
    int n = c & 7;
    t0[t] = x[((size_t)n * M_ + m) * FIN_ + f];
}

// row histogram
__global__ void k_hist(const int* __restrict__ row, int* __restrict__ cnt) {
    int i = blockIdx.x * blockDim.x + threadIdx.x;
    if (i < NNZ_) atomicAdd(&cnt[row[i]], 1);
}

// per-block sums of cnt (256 elems per block)
__global__ void k_blocksum(const int* __restrict__ cnt, int* __restrict__ bsum) {
    __shared__ int s[256];
    int t = threadIdx.x;
    int idx = blockIdx.x * 256 + t;
    s[t] = (idx < M_) ? cnt[idx] : 0;
    __syncthreads();
    for (int off = 128; off > 0; off >>= 1) {
        if (t < off) s[t] += s[t + off];
        __syncthreads();
    }
    if (t == 0) bsum[blockIdx.x] = s[0];
}

// single-block exclusive scan of bsum[SCAN_NB] -> boff[SCAN_NB]
__global__ void k_scan_bsum(const int* __restrict__ bsum, int* __restrict__ boff) {
    __shared__ int s[256];
    int t = threadIdx.x;
    int v = (t < SCAN_NB) ? bsum[t] : 0;
    s[t] = v;
    __syncthreads();
    for (int off = 1; off < 256; off <<= 1) {
        int a = (t >= off) ? s[t - off] : 0;
        __syncthreads();
        s[t] += a;
        __syncthreads();
    }
    if (t < SCAN_NB) boff[t] = s[t] - v;   // exclusive
}

// per-block local exclusive scan + global offset -> row_ptr, row_tmp
__global__ void k_emit(const int* __restrict__ cnt, const int* __restrict__ boff,
                       int* __restrict__ row_ptr, int* __restrict__ row_tmp) {
    __shared__ int s[256];
    int t = threadIdx.x;
    int idx = blockIdx.x * 256 + t;
    int v = (idx < M_) ? cnt[idx] : 0;
    s[t] = v;
    __syncthreads();
    for (int off = 1; off < 256; off <<= 1) {
        int a = (t >= off) ? s[t - off] : 0;
        __syncthreads();
        s[t] += a;
        __syncthreads();
    }
    if (idx < M_) {
        int r = boff[blockIdx.x] + s[t] - v;   // exclusive global offset
        row_ptr[idx] = r;
        row_tmp[idx] = r;
    }
    if (idx == 0) row_ptr[M_] = NNZ_;
}

// scatter nnz into CSR order, packing (val, col) into int2
__global__ void k_scatter(const float* __restrict__ vals, const int* __restrict__ row,
                          const int* __restrict__ col, int* __restrict__ row_tmp,
                          int2* __restrict__ pairs) {
    int i = blockIdx.x * blockDim.x + threadIdx.x;
    if (i >= NNZ_) return;
    int p = atomicAdd(&row_tmp[row[i]], 1);
    pairs[p] = make_int2(__float_as_int(vals[i]), col[i]);
}

// Y[r,:] = scale * sum_j v_j * X[c_j,:]  (- prev[r,:] if prev != null)
// one 32-lane group per row, float4 per lane
__global__ void k_spmm_csr(const float* __restrict__ X, const float* __restrict__ prev,
                           float* __restrict__ Y, const int* __restrict__ rp,
                           const int2* __restrict__ pairs, float scale) {
    int r = blockIdx.x * (blockDim.x >> 5) + (threadIdx.x >> 5);
    if (r >= M_) return;
    int c4 = (threadIdx.x & 31) * 4;
    float4 acc;
    if (prev) {
        float4 p = *reinterpret_cast<const float4*>(prev + (size_t)r * ROW_ + c4);
        acc = make_float4(-p.x, -p.y, -p.z, -p.w);
    } else {
        acc = make_float4(0.f, 0.f, 0.f, 0.f);
    }
    int e = rp[r + 1];
    for (int j = rp[r]; j < e; ++j) {
        int2 pc = pairs[j];
        float v = scale * __int_as_float(pc.x);
        const float4 xv = *reinterpret_cast<const float4*>(X + (size_t)pc.y * ROW_ + c4);
        acc.x += v * xv.x;
        acc.y += v * xv.y;
        acc.z += v * xv.z;
        acc.w += v * xv.w;
    }
    *reinterpret_cast<float4*>(Y + (size_t)r * ROW_ + c4) = acc;
}

// fused final einsum over all 4 terms: thread = (m, o), computes 8 n-outputs
__global__ void k_final(const float* __restrict__ T0, const float* __restrict__ T1,
                        const float* __restrict__ T2, const float* __restrict__ T3,
                        const float* __restrict__ w, const float* __restrict__ b,
                        float* __restrict__ out) {
    int t = blockIdx.x * blockDim.x + threadIdx.x;
    if (t >= M_ * FOUT_) return;
    int o = t & 31;
    int m = t >> 5;
    float acc[8];
    float bias = b[o];
#pragma unroll
    for (int n = 0; n < 8; ++n) acc[n] = bias;
    const float* Ts[4] = {T0, T1, T2, T3};
#pragma unroll
    for (int k = 0; k < 4; ++k) {
        const float* tr = Ts[k] + (size_t)m * ROW_;
#pragma unroll
        for (int f = 0; f < FIN_; ++f) {
            float wk = w[(f * KCH_ + k) * FOUT_ + o];
            float4 a0 = *reinterpret_cast<const float4*>(tr + f * 8);
            float4 a1 = *reinterpret_cast<const float4*>(tr + f * 8 + 4);
            acc[0] += a0.x * wk; acc[1] += a0.y * wk;
            acc[2] += a0.z * wk; acc[3] += a0.w * wk;
            acc[4] += a1.x * wk; acc[5] += a1.y * wk;
            acc[6] += a1.z * wk; acc[7] += a1.w * wk;
        }
    }
#pragma unroll
    for (int n = 0; n < 8; ++n)
        out[((size_t)n * M_ + m) * FOUT_ + o] = acc[n];
}

// per-term accumulation (fallback path, small ws): thread = (m, o), 8 n-outputs
__global__ void k_accum(const float* __restrict__ T, const float* __restrict__ w,
                        const float* __restrict__ b, float* __restrict__ out,
                        int k, int init) {
    int t = blockIdx.x * blockDim.x + threadIdx.x;
    if (t >= M_ * FOUT_) return;
    int o = t & 31;
    int m = t >> 5;
    float acc[8];
    if (init) {
        float bias = b[o];
#pragma unroll
        for (int n = 0; n < 8; ++n) acc[n] = bias;
    } else {
#pragma unroll
        for (int n = 0; n < 8; ++n) acc[n] = out[((size_t)n * M_ + m) * FOUT_ + o];
    }
    const float* tr = T + (size_t)m * ROW_;
#pragma unroll
    for (int f = 0; f < FIN_; ++f) {
        float wk = w[(f * KCH_ + k) * FOUT_ + o];
        float4 a0 = *reinterpret_cast<const float4*>(tr + f * 8);
        float4 a1 = *reinterpret_cast<const float4*>(tr + f * 8 + 4);
        acc[0] += a0.x * wk; acc[1] += a0.y * wk;
        acc[2] += a0.z * wk; acc[3] += a0.w * wk;
        acc[4] += a1.x * wk; acc[5] += a1.y * wk;
        acc[6] += a1.z * wk; acc[7] += a1.w * wk;
    }
#pragma unroll
    for (int n = 0; n < 8; ++n)
        out[((size_t)n * M_ + m) * FOUT_ + o] = acc[n];
}

// ---------------------------------------------------------------------------
extern "C" void kernel_launch(void* const* d_in, const int* in_sizes, int n_in,
                              void* d_out, int out_size, void* d_ws, size_t ws_size,
                              hipStream_t stream) {
    const float* x    = (const float*)d_in[0];
    const float* vals = (const float*)d_in[1];
    const float* w    = (const float*)d_in[2];
    const float* b    = (const float*)d_in[3];
    const int*   row  = (const int*)d_in[4];
    const int*   col  = (const int*)d_in[5];
    float* out = (float*)d_out;

    const size_t tElems = (size_t)M_ * ROW_;             // 6.4M floats per term
    const size_t csrBytes = (size_t)(M_ + 1) * 4 + (size_t)M_ * 4
                          + (size_t)NNZ_ * 8 + 2048;
    const size_t fusedBytes = 4 * tElems * 4 + csrBytes; // ~109 MB
    const bool fused = ws_size >= fusedBytes;

    float* T0 = (float*)d_ws;
    float* T1 = T0 + tElems;
    float* T2 = fused ? (T1 + tElems) : nullptr;
    float* T3 = fused ? (T2 + tElems) : nullptr;
    char*  p  = (char*)(fused ? (T3 + tElems) : (T1 + tElems));
    int*   row_ptr = (int*)p;              p += (size_t)(M_ + 1) * 4;
    int*   row_tmp = (int*)p;              p += (size_t)M_ * 4;
    int2*  pairs   = (int2*)p;             p += (size_t)NNZ_ * 8;
    int*   bsum    = (int*)p;              p += 1024;
    int*   boff    = (int*)p;

    const int TB = 256;
    dim3 blk(TB);
    dim3 gT(((int)tElems + TB - 1) / TB);          // term-sized elementwise
    dim3 gN((NNZ_ + TB - 1) / TB);                 // per-nnz
    dim3 gR((M_ * 32 + TB - 1) / TB);              // 32 lanes per row
    dim3 gF((M_ * FOUT_ + TB - 1) / TB);           // (m,o) threads

    // ---- build CSR (per call) ----
    hipMemsetAsync(row_tmp, 0, (size_t)M_ * 4, stream);     // row_tmp doubles as cnt
    hipLaunchKernelGGL(k_hist,      gN, blk, 0, stream, row, row_tmp);
    hipLaunchKernelGGL(k_blocksum,  dim3(SCAN_NB), blk, 0, stream, row_tmp, bsum);
    hipLaunchKernelGGL(k_scan_bsum, dim3(1), blk, 0, stream, bsum, boff);
    hipLaunchKernelGGL(k_emit,      dim3(SCAN_NB), blk, 0, stream, row_tmp, boff,
                       row_ptr, row_tmp);
    hipLaunchKernelGGL(k_scatter,   gN, blk, 0, stream, vals, row, col, row_tmp, pairs);

    // ---- Chebyshev terms ----
    hipLaunchKernelGGL(k_build_x0, gT, blk, 0, stream, x, T0);
    hipLaunchKernelGGL(k_spmm_csr, gR, blk, 0, stream, T0, (const float*)nullptr, T1,
                       row_ptr, pairs, 1.0f);

    if (fused) {
        hipLaunchKernelGGL(k_spmm_csr, gR, blk, 0, stream, T1, T0, T2,
                           row_ptr, pairs, 2.0f);
        hipLaunchKernelGGL(k_spmm_csr, gR, blk, 0, stream, T2, T1, T3,
                           row_ptr, pairs, 2.0f);
        hipLaunchKernelGGL(k_final, gF, blk, 0, stream, T0, T1, T2, T3, w, b, out);
    } else {
        hipLaunchKernelGGL(k_accum, gF, blk, 0, stream, T0, w, b, out, 0, 1);
        hipLaunchKernelGGL(k_accum, gF, blk, 0, stream, T1, w, b, out, 1, 0);
        hipLaunchKernelGGL(k_spmm_csr, gR, blk, 0, stream, T1, T0, T0,
                           row_ptr, pairs, 2.0f);        // T2 overwrites T0
        hipLaunchKernelGGL(k_accum, gF, blk, 0, stream, T0, w, b, out, 2, 0);
        hipLaunchKernelGGL(k_spmm_csr, gR, blk, 0, stream, T0, T1, T1,
                           row_ptr, pairs, 2.0f);        // T3 overwrites T1
        hipLaunchKernelGGL(k_accum, gF, blk, 0, stream, T1, w, b, out, 3, 0);
    }
}

// Round 4
// 404.481 us; speedup vs baseline: 10.5525x; 1.0310x over previous
//
#include <hip/hip_runtime.h>

// Problem constants (fixed-shape problem)
constexpr int N_    = 8;
constexpr int M_    = 50000;
constexpr int FIN_  = 16;
constexpr int FOUT_ = 32;
constexpr int KCH_  = 4;
constexpr int NNZ_  = 800000;
constexpr int ROW_  = FIN_ * N_;   // 128 floats per term row
constexpr int SCAN_NB = (M_ + 255) / 256;   // 196 scan blocks
constexpr int MT_   = 4;                    // m-values per thread in k_final
constexpr int MTILES_ = M_ / MT_;           // 12500 m-tiles (exact)

// ---------------------------------------------------------------------------
// X0[m, f*8+n] = x[n, m, f]
__global__ void k_build_x0(const float* __restrict__ x, float* __restrict__ t0) {
    int t = blockIdx.x * blockDim.x + threadIdx.x;
    if (t >= M_ * ROW_) return;
    int m = t >> 7;            // / 128
    int c = t & 127;
    int f = c >> 3;            // / 8
    int n = c & 7;
    t0[t] = x[((size_t)n * M_ + m) * FIN_ + f];
}

// row histogram
__global__ void k_hist(const int* __restrict__ row, int* __restrict__ cnt) {
    int i = blockIdx.x * blockDim.x + threadIdx.x;
    if (i < NNZ_) atomicAdd(&cnt[row[i]], 1);
}

// per-block sums of cnt (256 elems per block)
__global__ void k_blocksum(const int* __restrict__ cnt, int* __restrict__ bsum) {
    __shared__ int s[256];
    int t = threadIdx.x;
    int idx = blockIdx.x * 256 + t;
    s[t] = (idx < M_) ? cnt[idx] : 0;
    __syncthreads();
    for (int off = 128; off > 0; off >>= 1) {
        if (t < off) s[t] += s[t + off];
        __syncthreads();
    }
    if (t == 0) bsum[blockIdx.x] = s[0];
}

// single-block exclusive scan of bsum[SCAN_NB] -> boff[SCAN_NB]
__global__ void k_scan_bsum(const int* __restrict__ bsum, int* __restrict__ boff) {
    __shared__ int s[256];
    int t = threadIdx.x;
    int v = (t < SCAN_NB) ? bsum[t] : 0;
    s[t] = v;
    __syncthreads();
    for (int off = 1; off < 256; off <<= 1) {
        int a = (t >= off) ? s[t - off] : 0;
        __syncthreads();
        s[t] += a;
        __syncthreads();
    }
    if (t < SCAN_NB) boff[t] = s[t] - v;   // exclusive
}

// per-block local exclusive scan + global offset -> row_ptr, row_tmp
__global__ void k_emit(const int* __restrict__ cnt, const int* __restrict__ boff,
                       int* __restrict__ row_ptr, int* __restrict__ row_tmp) {
    __shared__ int s[256];
    int t = threadIdx.x;
    int idx = blockIdx.x * 256 + t;
    int v = (idx < M_) ? cnt[idx] : 0;
    s[t] = v;
    __syncthreads();
    for (int off = 1; off < 256; off <<= 1) {
        int a = (t >= off) ? s[t - off] : 0;
        __syncthreads();
        s[t] += a;
        __syncthreads();
    }
    if (idx < M_) {
        int r = boff[blockIdx.x] + s[t] - v;   // exclusive global offset
        row_ptr[idx] = r;
        row_tmp[idx] = r;
    }
    if (idx == 0) row_ptr[M_] = NNZ_;
}

// scatter nnz into CSR order, packing (val, col) into int2
__global__ void k_scatter(const float* __restrict__ vals, const int* __restrict__ row,
                          const int* __restrict__ col, int* __restrict__ row_tmp,
                          int2* __restrict__ pairs) {
    int i = blockIdx.x * blockDim.x + threadIdx.x;
    if (i >= NNZ_) return;
    int p = atomicAdd(&row_tmp[row[i]], 1);
    pairs[p] = make_int2(__float_as_int(vals[i]), col[i]);
}

// Y[r,:] = scale * sum_j v_j * X[c_j,:]  (- prev[r,:] if prev != null)
// one 32-lane group per row, float4 per lane
__global__ void k_spmm_csr(const float* __restrict__ X, const float* __restrict__ prev,
                           float* __restrict__ Y, const int* __restrict__ rp,
                           const int2* __restrict__ pairs, float scale) {
    int r = blockIdx.x * (blockDim.x >> 5) + (threadIdx.x >> 5);
    if (r >= M_) return;
    int c4 = (threadIdx.x & 31) * 4;
    float4 acc;
    if (prev) {
        float4 p = *reinterpret_cast<const float4*>(prev + (size_t)r * ROW_ + c4);
        acc = make_float4(-p.x, -p.y, -p.z, -p.w);
    } else {
        acc = make_float4(0.f, 0.f, 0.f, 0.f);
    }
    int e = rp[r + 1];
    for (int j = rp[r]; j < e; ++j) {
        int2 pc = pairs[j];
        float v = scale * __int_as_float(pc.x);
        const float4 xv = *reinterpret_cast<const float4*>(X + (size_t)pc.y * ROW_ + c4);
        acc.x += v * xv.x;
        acc.y += v * xv.y;
        acc.z += v * xv.z;
        acc.w += v * xv.w;
    }
    *reinterpret_cast<float4*>(Y + (size_t)r * ROW_ + c4) = acc;
}

// fused final einsum over all 4 terms.
// Thread = (n, 4 consecutive m), all 32 o in registers (float4 acc[4][8]).
// w staged in LDS (8 KB), read as broadcast ds_read_b128.
__global__ __launch_bounds__(256) void k_final(
        const float* __restrict__ T0, const float* __restrict__ T1,
        const float* __restrict__ T2, const float* __restrict__ T3,
        const float* __restrict__ w, const float* __restrict__ b,
        float* __restrict__ out) {
    __shared__ float lw[FIN_ * KCH_ * FOUT_];   // 2048 floats
    const int t = threadIdx.x;
    // stage w (coalesced float4)
    {
        const float4* ws = reinterpret_cast<const float4*>(w);
        float4* ld = reinterpret_cast<float4*>(lw);
#pragma unroll
        for (int i = 0; i < 2; ++i)
            ld[t + i * 256] = ws[t + i * 256];
    }
    __syncthreads();

    const int n   = t & 7;
    const int mt  = t >> 3;                      // 0..31
    const int mtg = blockIdx.x * 32 + mt;        // global m-tile
    if (mtg >= MTILES_) return;
    const int m0 = mtg * MT_;

    float4 acc[MT_][8];
    {
        const float4* bb = reinterpret_cast<const float4*>(b);
#pragma unroll
        for (int o4 = 0; o4 < 8; ++o4) {
            float4 bv = bb[o4];
#pragma unroll
            for (int i = 0; i < MT_; ++i) acc[i][o4] = bv;
        }
    }

    const float* Ts[4] = {T0, T1, T2, T3};
    for (int f = 0; f < FIN_; ++f) {
#pragma unroll
        for (int k = 0; k < KCH_; ++k) {
            const int fk = f * KCH_ + k;
            float tv[MT_];
#pragma unroll
            for (int i = 0; i < MT_; ++i)
                tv[i] = Ts[k][(size_t)(m0 + i) * ROW_ + f * 8 + n];
#pragma unroll
            for (int o4 = 0; o4 < 8; ++o4) {
                float4 wv = *reinterpret_cast<const float4*>(&lw[fk * FOUT_ + o4 * 4]);
#pragma unroll
                for (int i = 0; i < MT_; ++i) {
                    acc[i][o4].x += tv[i] * wv.x;
                    acc[i][o4].y += tv[i] * wv.y;
                    acc[i][o4].z += tv[i] * wv.z;
                    acc[i][o4].w += tv[i] * wv.w;
                }
            }
        }
    }

#pragma unroll
    for (int i = 0; i < MT_; ++i) {
        float* base = out + ((size_t)n * M_ + (m0 + i)) * FOUT_;
#pragma unroll
        for (int o4 = 0; o4 < 8; ++o4)
            *reinterpret_cast<float4*>(base + o4 * 4) = acc[i][o4];
    }
}

// per-term accumulation (fallback path, small ws): thread = (m, o), 8 n-outputs
__global__ void k_accum(const float* __restrict__ T, const float* __restrict__ w,
                        const float* __restrict__ b, float* __restrict__ out,
                        int k, int init) {
    int t = blockIdx.x * blockDim.x + threadIdx.x;
    if (t >= M_ * FOUT_) return;
    int o = t & 31;
    int m = t >> 5;
    float acc[8];
    if (init) {
        float bias = b[o];
#pragma unroll
        for (int n = 0; n < 8; ++n) acc[n] = bias;
    } else {
#pragma unroll
        for (int n = 0; n < 8; ++n) acc[n] = out[((size_t)n * M_ + m) * FOUT_ + o];
    }
    const float* tr = T + (size_t)m * ROW_;
#pragma unroll
    for (int f = 0; f < FIN_; ++f) {
        float wk = w[(f * KCH_ + k) * FOUT_ + o];
        float4 a0 = *reinterpret_cast<const float4*>(tr + f * 8);
        float4 a1 = *reinterpret_cast<const float4*>(tr + f * 8 + 4);
        acc[0] += a0.x * wk; acc[1] += a0.y * wk;
        acc[2] += a0.z * wk; acc[3] += a0.w * wk;
        acc[4] += a1.x * wk; acc[5] += a1.y * wk;
        acc[6] += a1.z * wk; acc[7] += a1.w * wk;
    }
#pragma unroll
    for (int n = 0; n < 8; ++n)
        out[((size_t)n * M_ + m) * FOUT_ + o] = acc[n];
}

// ---------------------------------------------------------------------------
extern "C" void kernel_launch(void* const* d_in, const int* in_sizes, int n_in,
                              void* d_out, int out_size, void* d_ws, size_t ws_size,
                              hipStream_t stream) {
    const float* x    = (const float*)d_in[0];
    const float* vals = (const float*)d_in[1];
    const float* w    = (const float*)d_in[2];
    const float* b    = (const float*)d_in[3];
    const int*   row  = (const int*)d_in[4];
    const int*   col  = (const int*)d_in[5];
    float* out = (float*)d_out;

    const size_t tElems = (size_t)M_ * ROW_;             // 6.4M floats per term
    const size_t csrBytes = (size_t)(M_ + 1) * 4 + (size_t)M_ * 4
                          + (size_t)NNZ_ * 8 + 2048;
    const size_t fusedBytes = 4 * tElems * 4 + csrBytes; // ~109 MB
    const bool fused = ws_size >= fusedBytes;

    float* T0 = (float*)d_ws;
    float* T1 = T0 + tElems;
    float* T2 = fused ? (T1 + tElems) : nullptr;
    float* T3 = fused ? (T2 + tElems) : nullptr;
    char*  p  = (char*)(fused ? (T3 + tElems) : (T1 + tElems));
    int*   row_ptr = (int*)p;              p += (size_t)(M_ + 1) * 4;
    int*   row_tmp = (int*)p;              p += (size_t)M_ * 4;
    int2*  pairs   = (int2*)p;             p += (size_t)NNZ_ * 8;
    int*   bsum    = (int*)p;              p += 1024;
    int*   boff    = (int*)p;

    const int TB = 256;
    dim3 blk(TB);
    dim3 gT(((int)tElems + TB - 1) / TB);          // term-sized elementwise
    dim3 gN((NNZ_ + TB - 1) / TB);                 // per-nnz
    dim3 gR((M_ * 32 + TB - 1) / TB);              // 32 lanes per row
    dim3 gF2((MTILES_ + 31) / 32);                 // k_final: 32 m-tiles per block
    dim3 gF((M_ * FOUT_ + TB - 1) / TB);           // fallback k_accum

    // ---- build CSR (per call) ----
    hipMemsetAsync(row_tmp, 0, (size_t)M_ * 4, stream);     // row_tmp doubles as cnt
    hipLaunchKernelGGL(k_hist,      gN, blk, 0, stream, row, row_tmp);
    hipLaunchKernelGGL(k_blocksum,  dim3(SCAN_NB), blk, 0, stream, row_tmp, bsum);
    hipLaunchKernelGGL(k_scan_bsum, dim3(1), blk, 0, stream, bsum, boff);
    hipLaunchKernelGGL(k_emit,      dim3(SCAN_NB), blk, 0, stream, row_tmp, boff,
                       row_ptr, row_tmp);
    hipLaunchKernelGGL(k_scatter,   gN, blk, 0, stream, vals, row, col, row_tmp, pairs);

    // ---- Chebyshev terms ----
    hipLaunchKernelGGL(k_build_x0, gT, blk, 0, stream, x, T0);
    hipLaunchKernelGGL(k_spmm_csr, gR, blk, 0, stream, T0, (const float*)nullptr, T1,
                       row_ptr, pairs, 1.0f);

    if (fused) {
        hipLaunchKernelGGL(k_spmm_csr, gR, blk, 0, stream, T1, T0, T2,
                           row_ptr, pairs, 2.0f);
        hipLaunchKernelGGL(k_spmm_csr, gR, blk, 0, stream, T2, T1, T3,
                           row_ptr, pairs, 2.0f);
        hipLaunchKernelGGL(k_final, gF2, blk, 0, stream, T0, T1, T2, T3, w, b, out);
    } else {
        hipLaunchKernelGGL(k_accum, gF, blk, 0, stream, T0, w, b, out, 0, 1);
        hipLaunchKernelGGL(k_accum, gF, blk, 0, stream, T1, w, b, out, 1, 0);
        hipLaunchKernelGGL(k_spmm_csr, gR, blk, 0, stream, T1, T0, T0,
                           row_ptr, pairs, 2.0f);        // T2 overwrites T0
        hipLaunchKernelGGL(k_accum, gF, blk, 0, stream, T0, w, b, out, 2, 0);
        hipLaunchKernelGGL(k_spmm_csr, gR, blk, 0, stream, T0, T1, T1,
                           row_ptr, pairs, 2.0f);        // T3 overwrites T1
        hipLaunchKernelGGL(k_accum, gF, blk, 0, stream, T1, w, b, out, 3, 0);
    }
}

// Round 5
// 358.385 us; speedup vs baseline: 11.9098x; 1.1286x over previous
//
#include <hip/hip_runtime.h>

// Problem constants (fixed-shape problem)
constexpr int N_    = 8;
constexpr int M_    = 50000;
constexpr int FIN_  = 16;
constexpr int FOUT_ = 32;
constexpr int KCH_  = 4;
constexpr int NNZ_  = 800000;
constexpr int ROW_  = FIN_ * N_;   // 128 floats per term row
constexpr int SCAN_NB = (M_ + 255) / 256;   // 196 scan blocks
constexpr int MT_   = 2;                    // m-values per thread in k_final
constexpr int MTILES_ = M_ / MT_;           // 25000 m-tiles (exact)

// ---------------------------------------------------------------------------
// X0[m, f*8+n] = x[n, m, f]
__global__ void k_build_x0(const float* __restrict__ x, float* __restrict__ t0) {
    int t = blockIdx.x * blockDim.x + threadIdx.x;
    if (t >= M_ * ROW_) return;
    int m = t >> 7;            // / 128
    int c = t & 127;
    int f = c >> 3;            // / 8
    int n = c & 7;
    t0[t] = x[((size_t)n * M_ + m) * FIN_ + f];
}

// row histogram
__global__ void k_hist(const int* __restrict__ row, int* __restrict__ cnt) {
    int i = blockIdx.x * blockDim.x + threadIdx.x;
    if (i < NNZ_) atomicAdd(&cnt[row[i]], 1);
}

// per-block sums of cnt (256 elems per block)
__global__ void k_blocksum(const int* __restrict__ cnt, int* __restrict__ bsum) {
    __shared__ int s[256];
    int t = threadIdx.x;
    int idx = blockIdx.x * 256 + t;
    s[t] = (idx < M_) ? cnt[idx] : 0;
    __syncthreads();
    for (int off = 128; off > 0; off >>= 1) {
        if (t < off) s[t] += s[t + off];
        __syncthreads();
    }
    if (t == 0) bsum[blockIdx.x] = s[0];
}

// single-block exclusive scan of bsum[SCAN_NB] -> boff[SCAN_NB]
__global__ void k_scan_bsum(const int* __restrict__ bsum, int* __restrict__ boff) {
    __shared__ int s[256];
    int t = threadIdx.x;
    int v = (t < SCAN_NB) ? bsum[t] : 0;
    s[t] = v;
    __syncthreads();
    for (int off = 1; off < 256; off <<= 1) {
        int a = (t >= off) ? s[t - off] : 0;
        __syncthreads();
        s[t] += a;
        __syncthreads();
    }
    if (t < SCAN_NB) boff[t] = s[t] - v;   // exclusive
}

// per-block local exclusive scan + global offset -> row_ptr, row_tmp
__global__ void k_emit(const int* __restrict__ cnt, const int* __restrict__ boff,
                       int* __restrict__ row_ptr, int* __restrict__ row_tmp) {
    __shared__ int s[256];
    int t = threadIdx.x;
    int idx = blockIdx.x * 256 + t;
    int v = (idx < M_) ? cnt[idx] : 0;
    s[t] = v;
    __syncthreads();
    for (int off = 1; off < 256; off <<= 1) {
        int a = (t >= off) ? s[t - off] : 0;
        __syncthreads();
        s[t] += a;
        __syncthreads();
    }
    if (idx < M_) {
        int r = boff[blockIdx.x] + s[t] - v;   // exclusive global offset
        row_ptr[idx] = r;
        row_tmp[idx] = r;
    }
    if (idx == 0) row_ptr[M_] = NNZ_;
}

// scatter nnz into CSR order, packing (val, col) into int2
__global__ void k_scatter(const float* __restrict__ vals, const int* __restrict__ row,
                          const int* __restrict__ col, int* __restrict__ row_tmp,
                          int2* __restrict__ pairs) {
    int i = blockIdx.x * blockDim.x + threadIdx.x;
    if (i >= NNZ_) return;
    int p = atomicAdd(&row_tmp[row[i]], 1);
    pairs[p] = make_int2(__float_as_int(vals[i]), col[i]);
}

// Y[r,:] = scale * sum_j v_j * X[c_j,:]  (- prev[r,:] if prev != null)
// one 32-lane group per row, float4 per lane
__global__ void k_spmm_csr(const float* __restrict__ X, const float* __restrict__ prev,
                           float* __restrict__ Y, const int* __restrict__ rp,
                           const int2* __restrict__ pairs, float scale) {
    int r = blockIdx.x * (blockDim.x >> 5) + (threadIdx.x >> 5);
    if (r >= M_) return;
    int c4 = (threadIdx.x & 31) * 4;
    float4 acc;
    if (prev) {
        float4 p = *reinterpret_cast<const float4*>(prev + (size_t)r * ROW_ + c4);
        acc = make_float4(-p.x, -p.y, -p.z, -p.w);
    } else {
        acc = make_float4(0.f, 0.f, 0.f, 0.f);
    }
    int e = rp[r + 1];
    for (int j = rp[r]; j < e; ++j) {
        int2 pc = pairs[j];
        float v = scale * __int_as_float(pc.x);
        const float4 xv = *reinterpret_cast<const float4*>(X + (size_t)pc.y * ROW_ + c4);
        acc.x += v * xv.x;
        acc.y += v * xv.y;
        acc.z += v * xv.z;
        acc.w += v * xv.w;
    }
    *reinterpret_cast<float4*>(Y + (size_t)r * ROW_ + c4) = acc;
}

// fused final einsum over all 4 terms.
// Thread = (n, 2 consecutive m), all 32 o in registers (float4 acc[2][8] = 64 VGPR).
// w/b accessed with wave-uniform indices -> scalar (s_load) or single-transaction
// broadcast loads from K$/L1 (w is 8 KB, fully cache-resident). No LDS.
__global__ __launch_bounds__(256, 4) void k_final(
        const float* __restrict__ T0, const float* __restrict__ T1,
        const float* __restrict__ T2, const float* __restrict__ T3,
        const float* __restrict__ w, const float* __restrict__ b,
        float* __restrict__ out) {
    int t = blockIdx.x * blockDim.x + threadIdx.x;
    if (t >= MTILES_ * N_) return;
    const int n  = t & 7;
    const int m0 = (t >> 3) * MT_;

    float4 acc[MT_][8];
#pragma unroll
    for (int o4 = 0; o4 < 8; ++o4) {
        float4 bv = *reinterpret_cast<const float4*>(b + o4 * 4);   // uniform
#pragma unroll
        for (int i = 0; i < MT_; ++i) acc[i][o4] = bv;
    }

    const float* Ts[4] = {T0, T1, T2, T3};
#pragma unroll
    for (int k = 0; k < KCH_; ++k) {
        const float* tb = Ts[k] + (size_t)m0 * ROW_ + n;
#pragma unroll
        for (int f = 0; f < FIN_; ++f) {
            float tv0 = tb[f * 8];            // imm-offset loads off one base
            float tv1 = tb[f * 8 + ROW_];
            const float* wr = w + (f * KCH_ + k) * FOUT_;   // uniform
#pragma unroll
            for (int o4 = 0; o4 < 8; ++o4) {
                float4 wv = *reinterpret_cast<const float4*>(wr + o4 * 4);
                acc[0][o4].x += tv0 * wv.x;
                acc[0][o4].y += tv0 * wv.y;
                acc[0][o4].z += tv0 * wv.z;
                acc[0][o4].w += tv0 * wv.w;
                acc[1][o4].x += tv1 * wv.x;
                acc[1][o4].y += tv1 * wv.y;
                acc[1][o4].z += tv1 * wv.z;
                acc[1][o4].w += tv1 * wv.w;
            }
        }
    }

#pragma unroll
    for (int i = 0; i < MT_; ++i) {
        float* base = out + ((size_t)n * M_ + (m0 + i)) * FOUT_;
#pragma unroll
        for (int o4 = 0; o4 < 8; ++o4)
            *reinterpret_cast<float4*>(base + o4 * 4) = acc[i][o4];
    }
}

// per-term accumulation (fallback path, small ws): thread = (m, o), 8 n-outputs
__global__ void k_accum(const float* __restrict__ T, const float* __restrict__ w,
                        const float* __restrict__ b, float* __restrict__ out,
                        int k, int init) {
    int t = blockIdx.x * blockDim.x + threadIdx.x;
    if (t >= M_ * FOUT_) return;
    int o = t & 31;
    int m = t >> 5;
    float acc[8];
    if (init) {
        float bias = b[o];
#pragma unroll
        for (int n = 0; n < 8; ++n) acc[n] = bias;
    } else {
#pragma unroll
        for (int n = 0; n < 8; ++n) acc[n] = out[((size_t)n * M_ + m) * FOUT_ + o];
    }
    const float* tr = T + (size_t)m * ROW_;
#pragma unroll
    for (int f = 0; f < FIN_; ++f) {
        float wk = w[(f * KCH_ + k) * FOUT_ + o];
        float4 a0 = *reinterpret_cast<const float4*>(tr + f * 8);
        float4 a1 = *reinterpret_cast<const float4*>(tr + f * 8 + 4);
        acc[0] += a0.x * wk; acc[1] += a0.y * wk;
        acc[2] += a0.z * wk; acc[3] += a0.w * wk;
        acc[4] += a1.x * wk; acc[5] += a1.y * wk;
        acc[6] += a1.z * wk; acc[7] += a1.w * wk;
    }
#pragma unroll
    for (int n = 0; n < 8; ++n)
        out[((size_t)n * M_ + m) * FOUT_ + o] = acc[n];
}

// ---------------------------------------------------------------------------
extern "C" void kernel_launch(void* const* d_in, const int* in_sizes, int n_in,
                              void* d_out, int out_size, void* d_ws, size_t ws_size,
                              hipStream_t stream) {
    const float* x    = (const float*)d_in[0];
    const float* vals = (const float*)d_in[1];
    const float* w    = (const float*)d_in[2];
    const float* b    = (const float*)d_in[3];
    const int*   row  = (const int*)d_in[4];
    const int*   col  = (const int*)d_in[5];
    float* out = (float*)d_out;

    const size_t tElems = (size_t)M_ * ROW_;             // 6.4M floats per term
    const size_t csrBytes = (size_t)(M_ + 1) * 4 + (size_t)M_ * 4
                          + (size_t)NNZ_ * 8 + 2048;
    const size_t fusedBytes = 4 * tElems * 4 + csrBytes; // ~109 MB
    const bool fused = ws_size >= fusedBytes;

    float* T0 = (float*)d_ws;
    float* T1 = T0 + tElems;
    float* T2 = fused ? (T1 + tElems) : nullptr;
    float* T3 = fused ? (T2 + tElems) : nullptr;
    char*  p  = (char*)(fused ? (T3 + tElems) : (T1 + tElems));
    int*   row_ptr = (int*)p;              p += (size_t)(M_ + 1) * 4;
    int*   row_tmp = (int*)p;              p += (size_t)M_ * 4;
    int2*  pairs   = (int2*)p;             p += (size_t)NNZ_ * 8;
    int*   bsum    = (int*)p;              p += 1024;
    int*   boff    = (int*)p;

    const int TB = 256;
    dim3 blk(TB);
    dim3 gT(((int)tElems + TB - 1) / TB);          // term-sized elementwise
    dim3 gN((NNZ_ + TB - 1) / TB);                 // per-nnz
    dim3 gR((M_ * 32 + TB - 1) / TB);              // 32 lanes per row
    dim3 gF2((MTILES_ * N_ + TB - 1) / TB);        // k_final threads
    dim3 gF((M_ * FOUT_ + TB - 1) / TB);           // fallback k_accum

    // ---- build CSR (per call) ----
    hipMemsetAsync(row_tmp, 0, (size_t)M_ * 4, stream);     // row_tmp doubles as cnt
    hipLaunchKernelGGL(k_hist,      gN, blk, 0, stream, row, row_tmp);
    hipLaunchKernelGGL(k_blocksum,  dim3(SCAN_NB), blk, 0, stream, row_tmp, bsum);
    hipLaunchKernelGGL(k_scan_bsum, dim3(1), blk, 0, stream, bsum, boff);
    hipLaunchKernelGGL(k_emit,      dim3(SCAN_NB), blk, 0, stream, row_tmp, boff,
                       row_ptr, row_tmp);
    hipLaunchKernelGGL(k_scatter,   gN, blk, 0, stream, vals, row, col, row_tmp, pairs);

    // ---- Chebyshev terms ----
    hipLaunchKernelGGL(k_build_x0, gT, blk, 0, stream, x, T0);
    hipLaunchKernelGGL(k_spmm_csr, gR, blk, 0, stream, T0, (const float*)nullptr, T1,
                       row_ptr, pairs, 1.0f);

    if (fused) {
        hipLaunchKernelGGL(k_spmm_csr, gR, blk, 0, stream, T1, T0, T2,
                           row_ptr, pairs, 2.0f);
        hipLaunchKernelGGL(k_spmm_csr, gR, blk, 0, stream, T2, T1, T3,
                           row_ptr, pairs, 2.0f);
        hipLaunchKernelGGL(k_final, gF2, blk, 0, stream, T0, T1, T2, T3, w, b, out);
    } else {
        hipLaunchKernelGGL(k_accum, gF, blk, 0, stream, T0, w, b, out, 0, 1);
        hipLaunchKernelGGL(k_accum, gF, blk, 0, stream, T1, w, b, out, 1, 0);
        hipLaunchKernelGGL(k_spmm_csr, gR, blk, 0, stream, T1, T0, T0,
                           row_ptr, pairs, 2.0f);        // T2 overwrites T0
        hipLaunchKernelGGL(k_accum, gF, blk, 0, stream, T0, w, b, out, 2, 0);
        hipLaunchKernelGGL(k_spmm_csr, gR, blk, 0, stream, T0, T1, T1,
                           row_ptr, pairs, 2.0f);        // T3 overwrites T1
        hipLaunchKernelGGL(k_accum, gF, blk, 0, stream, T1, w, b, out, 3, 0);
    }
}